// Round 3
// baseline (399.032 us; speedup 1.0000x reference)
//
#include <hip/hip_runtime.h>

// src [2,2,160,192,160] f32, flow [2,3,160,192,160] f32, out [2,2,160,192,160] f32
#define BB 2
#define CC 2
#define DD 160
#define HH 192
#define WW 160
#define NN (DD * HH * WW)

__global__ __launch_bounds__(256) void st_warp3d_kernel(
    const float* __restrict__ src,
    const float* __restrict__ flow,
    float* __restrict__ out)
{
    const int tid = blockIdx.x * blockDim.x + threadIdx.x;
    const int total = BB * NN;  // 9,830,400
    if (tid >= total) return;

    const int b = (tid >= NN) ? 1 : 0;
    const int n = tid - b * NN;
    const int x = n % WW;
    const int t = n / WW;
    const int y = t % HH;
    const int z = t / HH;

    const float* fl = flow + (size_t)b * 3 * NN + n;
    const float zc = (float)z + fl[0];
    const float yc = (float)y + fl[NN];
    const float xc = (float)x + fl[2 * (size_t)NN];

    const float z0f = floorf(zc), y0f = floorf(yc), x0f = floorf(xc);
    const float fz = zc - z0f, fy = yc - y0f, fx = xc - x0f;
    const int z0 = (int)z0f, y0 = (int)y0f, x0 = (int)x0f;
    const int z1 = z0 + 1, y1 = y0 + 1, x1 = x0 + 1;

    // per-axis weights with out-of-bounds masking folded in (zero-padding)
    const float wz0 = (z0 >= 0 && z0 < DD) ? (1.0f - fz) : 0.0f;
    const float wz1 = (z1 >= 0 && z1 < DD) ? fz : 0.0f;
    const float wy0 = (y0 >= 0 && y0 < HH) ? (1.0f - fy) : 0.0f;
    const float wy1 = (y1 >= 0 && y1 < HH) ? fy : 0.0f;
    const float wx0 = (x0 >= 0 && x0 < WW) ? (1.0f - fx) : 0.0f;
    const float wx1 = (x1 >= 0 && x1 < WW) ? fx : 0.0f;

    // clamped row indices
    const int z0c = min(max(z0, 0), DD - 1);
    const int z1c = min(max(z1, 0), DD - 1);
    const int y0c = min(max(y0, 0), HH - 1);
    const int y1c = min(max(y1, 0), HH - 1);

    // x-pair base: float2 load covers both x corners (selectors fix boundaries;
    // any corner whose value matters has weight != 0 only when in-bounds)
    const int xb = min(max(x0, 0), WW - 2);
    const bool selA = (x0 == xb);  // a000 = selA ? p.x : p.y
    const bool selB = (x1 == xb);  // a001 = selB ? p.x : p.y

    const int r00 = (z0c * HH + y0c) * WW + xb;
    const int r01 = (z0c * HH + y1c) * WW + xb;
    const int r10 = (z1c * HH + y0c) * WW + xb;
    const int r11 = (z1c * HH + y1c) * WW + xb;

    const float* s0 = src + (size_t)b * CC * NN;  // channel 0
    const float* s1 = s0 + NN;                    // channel 1

    // 8 float2 gathers (4 rows x 2 channels) — all independent, issued up front
    const float2 pa00 = *(const float2*)(s0 + r00);
    const float2 pa01 = *(const float2*)(s0 + r01);
    const float2 pa10 = *(const float2*)(s0 + r10);
    const float2 pa11 = *(const float2*)(s0 + r11);
    const float2 pb00 = *(const float2*)(s1 + r00);
    const float2 pb01 = *(const float2*)(s1 + r01);
    const float2 pb10 = *(const float2*)(s1 + r10);
    const float2 pb11 = *(const float2*)(s1 + r11);

    const float w00 = wz0 * wy0, w01 = wz0 * wy1, w10 = wz1 * wy0, w11 = wz1 * wy1;
    const float w000 = w00 * wx0, w001 = w00 * wx1;
    const float w010 = w01 * wx0, w011 = w01 * wx1;
    const float w100 = w10 * wx0, w101 = w10 * wx1;
    const float w110 = w11 * wx0, w111 = w11 * wx1;

    const float a000 = selA ? pa00.x : pa00.y, a001 = selB ? pa00.x : pa00.y;
    const float a010 = selA ? pa01.x : pa01.y, a011 = selB ? pa01.x : pa01.y;
    const float a100 = selA ? pa10.x : pa10.y, a101 = selB ? pa10.x : pa10.y;
    const float a110 = selA ? pa11.x : pa11.y, a111 = selB ? pa11.x : pa11.y;
    const float b000 = selA ? pb00.x : pb00.y, b001 = selB ? pb00.x : pb00.y;
    const float b010 = selA ? pb01.x : pb01.y, b011 = selB ? pb01.x : pb01.y;
    const float b100 = selA ? pb10.x : pb10.y, b101 = selB ? pb10.x : pb10.y;
    const float b110 = selA ? pb11.x : pb11.y, b111 = selB ? pb11.x : pb11.y;

    const float acc0 = a000 * w000 + a001 * w001 + a010 * w010 + a011 * w011 +
                       a100 * w100 + a101 * w101 + a110 * w110 + a111 * w111;
    const float acc1 = b000 * w000 + b001 * w001 + b010 * w010 + b011 * w011 +
                       b100 * w100 + b101 * w101 + b110 * w110 + b111 * w111;

    float* o = out + (size_t)b * CC * NN + n;
    o[0] = acc0;
    o[NN] = acc1;
}

extern "C" void kernel_launch(void* const* d_in, const int* in_sizes, int n_in,
                              void* d_out, int out_size, void* d_ws, size_t ws_size,
                              hipStream_t stream) {
    const float* src  = (const float*)d_in[0];
    const float* flow = (const float*)d_in[1];
    float* out = (float*)d_out;

    const int total = BB * NN;
    const int block = 256;
    const int grid = (total + block - 1) / block;

    st_warp3d_kernel<<<grid, block, 0, stream>>>(src, flow, out);
}